// Round 2
// baseline (395.988 us; speedup 1.0000x reference)
//
#include <hip/hip_runtime.h>

#define L 5
#define C 256
#define HH 128
#define WW 384
#define N (HH * WW)  // 49152

// ---------------------------------------------------------------------------
// K1: z[l,n] = sum_c feats[l,c,n] * w[c]
// One thread per (l, n). Consecutive threads -> consecutive n (coalesced).
// ---------------------------------------------------------------------------
__global__ __launch_bounds__(256) void k_z(const float* __restrict__ feats,
                                           const float* __restrict__ w,
                                           float* __restrict__ z) {
    __shared__ float wl[C];
    const int tid = threadIdx.x;
    wl[tid] = w[tid];  // blockDim.x == 256 == C
    __syncthreads();

    const int BPL = N / 256;  // 192 blocks per agent
    const int l = blockIdx.x / BPL;
    const int n = (blockIdx.x % BPL) * 256 + tid;

    const float* fp = feats + (size_t)l * C * N + n;
    float acc = 0.f;
#pragma unroll 8
    for (int c = 0; c < C; ++c) {
        acc += fp[(size_t)c * N] * wl[c];
    }
    z[l * N + n] = acc;
}

// ---------------------------------------------------------------------------
// K2: per-pixel Shapley values over 5 agents + softmax; overwrites z with
// softmax weights in place (each thread owns one n across all l -> no hazard).
// ---------------------------------------------------------------------------
__global__ __launch_bounds__(256) void k_shap(const float* __restrict__ bptr,
                                              float* __restrict__ z) {
    const int n = blockIdx.x * 256 + threadIdx.x;
    const float bv = bptr[0];

    float zv[L];
#pragma unroll
    for (int l = 0; l < L; ++l) zv[l] = z[l * N + n];

    // weight by |S| (subset of the other 4): card!(4-card)!/5!
    const float wc1 = 0.05f;        // 1!*3!/120
    const float wc2 = 1.f / 30.f;   // 2!*2!/120
    const float wc3 = 0.05f;        // 3!*1!/120
    const float wc4 = 0.2f;         // 4!*0!/120
    const float wcard[5] = {0.f, wc1, wc2, wc3, wc4};

    float shap[L];
#pragma unroll
    for (int i = 0; i < L; ++i) {
        // others = the 4 agents != i (compile-time after full unroll)
        int others[4];
        {
            int k = 0;
#pragma unroll
            for (int j = 0; j < L; ++j)
                if (j != i) others[k++] = j;
        }
        float acc = 0.f;
#pragma unroll
        for (int m = 1; m < 16; ++m) {
            float s = zv[i] + bv;
            int card = 0;
#pragma unroll
            for (int kk = 0; kk < 4; ++kk) {
                if ((m >> kk) & 1) { s += zv[others[kk]]; ++card; }
            }
            acc += wcard[card] * fmaxf(s, 0.f);
        }
        const float self = fmaxf(zv[i] + bv, 0.f);
        // sum(wgt) = 0.8 ; shap = acc - 0.8*self + self/5 = acc - 0.6*self
        shap[i] = acc - 0.6f * self;
    }

    // softmax over agents
    float mx = shap[0];
#pragma unroll
    for (int i = 1; i < L; ++i) mx = fmaxf(mx, shap[i]);
    float e[L];
    float sum = 0.f;
#pragma unroll
    for (int i = 0; i < L; ++i) { e[i] = __expf(shap[i] - mx); sum += e[i]; }
    const float inv = 1.f / sum;
#pragma unroll
    for (int i = 0; i < L; ++i) z[i * N + n] = e[i] * inv;
}

// ---------------------------------------------------------------------------
// K3: out[c,n] = sum_l feats[l,c,n] * wsoft[l,n]   (float4 over n)
// wsoft (983 KB) stays L2-resident across the C re-reads.
// ---------------------------------------------------------------------------
__global__ __launch_bounds__(256) void k_out(const float* __restrict__ feats,
                                             const float* __restrict__ wsoft,
                                             float* __restrict__ out) {
    const int tid = threadIdx.x;
    const int BPC = (N / 4) / 256;  // 48 blocks per channel
    const int c = blockIdx.x / BPC;
    const int n = ((blockIdx.x % BPC) * 256 + tid) * 4;

    float4 acc = make_float4(0.f, 0.f, 0.f, 0.f);
#pragma unroll
    for (int l = 0; l < L; ++l) {
        const float4 f = *(const float4*)(feats + ((size_t)(l * C + c)) * N + n);
        const float4 s = *(const float4*)(wsoft + (size_t)l * N + n);
        acc.x += f.x * s.x;
        acc.y += f.y * s.y;
        acc.z += f.z * s.z;
        acc.w += f.w * s.w;
    }
    *(float4*)(out + (size_t)c * N + n) = acc;
}

extern "C" void kernel_launch(void* const* d_in, const int* in_sizes, int n_in,
                              void* d_out, int out_size, void* d_ws, size_t ws_size,
                              hipStream_t stream) {
    const float* feats = (const float*)d_in[0];
    const float* w     = (const float*)d_in[1];
    const float* bptr  = (const float*)d_in[2];
    float* out = (float*)d_out;
    float* z   = (float*)d_ws;  // L*N floats = 3.93 MB (z, then wsoft in place)

    k_z<<<L * (N / 256), 256, 0, stream>>>(feats, w, z);
    k_shap<<<N / 256, 256, 0, stream>>>(bptr, z);
    k_out<<<C * ((N / 4) / 256), 256, 0, stream>>>(feats, z, out);
}

// Round 3
// 371.228 us; speedup vs baseline: 1.0667x; 1.0667x over previous
//
#include <hip/hip_runtime.h>

#define L 5
#define C 256
#define HH 128
#define WW 384
#define N (HH * WW)   // 49152
#define TN 8          // pixels per block
#define NBLK (N / TN) // 6144 blocks
#define ROWS (L * C)  // 1280 rows of feats, row r = l*256+c

// One fused kernel: single read of feats.
// Phase 1: stream feats[*, *, n0:n0+8] -> LDS tile (40 KB) while accumulating
//          z[l,n] = sum_c w[c]*feats[l,c,n] (regs -> shfl reduce -> LDS atomics).
// Phase 2: 8 threads compute Shapley + softmax over agents for their pixel.
// Phase 3: out[c,n] = sum_l tile[l][c][n] * wsoft[l][n], conflict-free LDS reads.
__global__ __launch_bounds__(256) void k_fused(const float* __restrict__ feats,
                                               const float* __restrict__ w,
                                               const float* __restrict__ bptr,
                                               float* __restrict__ out) {
    // LDS: tile as float4-indexed rows: f4 index f = r*2 + n4  (r = l*256+c)
    __shared__ float tile[ROWS * TN];  // 40 KB
    __shared__ float wlds[C];
    __shared__ float zl[L][TN];
    __shared__ float wsl[L][TN];

    const int t = threadIdx.x;

    // XCD-chunked swizzle: consecutive n-tiles land on the same XCD so adjacent
    // 32 B column reads merge into one 128 B HBM line fetch. 6144 = 8 * 768.
    const int blk = (blockIdx.x & 7) * (NBLK / 8) + (blockIdx.x >> 3);
    const int n0 = blk * TN;

    wlds[t] = w[t];                       // blockDim == C == 256
    if (t < L * TN) ((float*)zl)[t] = 0.f;
    __syncthreads();

    const float bv = bptr[0];
    const int n4 = t & 1;    // which float4 within the 8-float row
    const int r0 = t >> 1;   // base row (0..127)

    // ---- Phase 1: load + z partial accumulation ----
    float za = 0.f, zb = 0.f, zc = 0.f, zd = 0.f;
#pragma unroll
    for (int k = 0; k < 10; ++k) {
        const int r = r0 + 128 * k;        // covers all 1280 rows across threads
        const int c = r & 255;
        const float4 v = *(const float4*)(feats + (size_t)r * N + n0 + n4 * 4);
        *(float4*)(&tile[(size_t)(t + 256 * k) * 4]) = v;  // lane-consecutive, conflict-free
        const float wc = wlds[c];
        za += wc * v.x; zb += wc * v.y; zc += wc * v.z; zd += wc * v.w;
        if (k & 1) {
            // finished agent l = k>>1 (r0 < 128 so l is uniform across threads)
            // reduce over the 32 lanes of this wave sharing n4 (xor strides keep t&1)
            float s0 = za, s1 = zb, s2 = zc, s3 = zd;
#pragma unroll
            for (int st = 2; st <= 32; st <<= 1) {
                s0 += __shfl_xor(s0, st);
                s1 += __shfl_xor(s1, st);
                s2 += __shfl_xor(s2, st);
                s3 += __shfl_xor(s3, st);
            }
            if ((t & 63) < 2) {  // one lane per n4 per wave
                const int l = k >> 1;
                const int nn = n4 * 4;
                atomicAdd(&zl[l][nn + 0], s0);
                atomicAdd(&zl[l][nn + 1], s1);
                atomicAdd(&zl[l][nn + 2], s2);
                atomicAdd(&zl[l][nn + 3], s3);
            }
            za = zb = zc = zd = 0.f;
        }
    }
    __syncthreads();

    // ---- Phase 2: Shapley + softmax (8 threads, one per pixel) ----
    if (t < TN) {
        float zv[L];
#pragma unroll
        for (int l = 0; l < L; ++l) zv[l] = zl[l][t];

        const float wcard[5] = {0.f, 0.05f, 1.f / 30.f, 0.05f, 0.2f};
        float shap[L];
#pragma unroll
        for (int i = 0; i < L; ++i) {
            int others[4];
            int kk = 0;
#pragma unroll
            for (int j = 0; j < L; ++j)
                if (j != i) others[kk++] = j;
            float acc = 0.f;
#pragma unroll
            for (int m = 1; m < 16; ++m) {
                float s = zv[i] + bv;
                int card = 0;
#pragma unroll
                for (int q = 0; q < 4; ++q)
                    if ((m >> q) & 1) { s += zv[others[q]]; ++card; }
                acc += wcard[card] * fmaxf(s, 0.f);
            }
            const float self = fmaxf(zv[i] + bv, 0.f);
            shap[i] = acc - 0.6f * self;  // -sum(wgt)=-0.8, +1/L=+0.2
        }
        float mx = shap[0];
#pragma unroll
        for (int i = 1; i < L; ++i) mx = fmaxf(mx, shap[i]);
        float e[L], sum = 0.f;
#pragma unroll
        for (int i = 0; i < L; ++i) { e[i] = __expf(shap[i] - mx); sum += e[i]; }
        const float inv = 1.f / sum;
#pragma unroll
        for (int i = 0; i < L; ++i) wsl[i][t] = e[i] * inv;
    }
    __syncthreads();

    // ---- Phase 3: weighted combine from LDS, write out ----
    float wr[L][4];
#pragma unroll
    for (int l = 0; l < L; ++l)
#pragma unroll
        for (int j = 0; j < 4; ++j) wr[l][j] = wsl[l][n4 * 4 + j];

#pragma unroll
    for (int k2 = 0; k2 < 2; ++k2) {
        const int c = r0 + 128 * k2;
        float4 acc = make_float4(0.f, 0.f, 0.f, 0.f);
#pragma unroll
        for (int l = 0; l < L; ++l) {
            // f4 index = (l*256+c)*2 + n4 = l*512 + t + 256*k2 -> lane-consecutive
            const float4 f = *(const float4*)(&tile[(size_t)(l * 512 + t + 256 * k2) * 4]);
            acc.x += f.x * wr[l][0];
            acc.y += f.y * wr[l][1];
            acc.z += f.z * wr[l][2];
            acc.w += f.w * wr[l][3];
        }
        *(float4*)(out + (size_t)c * N + n0 + n4 * 4) = acc;
    }
}

extern "C" void kernel_launch(void* const* d_in, const int* in_sizes, int n_in,
                              void* d_out, int out_size, void* d_ws, size_t ws_size,
                              hipStream_t stream) {
    const float* feats = (const float*)d_in[0];
    const float* w     = (const float*)d_in[1];
    const float* bptr  = (const float*)d_in[2];
    float* out = (float*)d_out;

    k_fused<<<NBLK, 256, 0, stream>>>(feats, w, bptr, out);
}

// Round 4
// 364.402 us; speedup vs baseline: 1.0867x; 1.0187x over previous
//
#include <hip/hip_runtime.h>

#define L 5
#define C 256
#define HH 128
#define WW 384
#define N (HH * WW)    // 49152
#define TN 16          // pixels per block
#define NBLK (N / TN)  // 3072 blocks
#define ROWS (L * C)   // 1280 rows, row r = l*256+c

// bf16 round-to-nearest-even pack (inputs finite)
__device__ __forceinline__ unsigned short bf16rne(float x) {
    unsigned int u = __float_as_uint(x);
    return (unsigned short)((u + 0x7FFFu + ((u >> 16) & 1u)) >> 16);
}
__device__ __forceinline__ float bf16tof(unsigned short h) {
    unsigned int u = ((unsigned int)h) << 16;
    return __uint_as_float(u);
}

// One fused kernel, single feats read (302 MB total HBM traffic).
// Phase 1: stream feats[*,*,n0:n0+16] -> bf16 LDS tile (40 KB) while
//          accumulating z[l,n] = sum_c w[c]*f (f32, pre-rounding) in regs;
//          shfl-reduce per agent -> LDS atomics.
// Phase 2: 16 threads do Shapley + softmax per pixel.
// Phase 3: out[c,n] = sum_l bf16(tile) * wsoft, 64B/row global stores.
__global__ __launch_bounds__(256) void k_fused(const float* __restrict__ feats,
                                               const float* __restrict__ w,
                                               const float* __restrict__ bptr,
                                               float* __restrict__ out) {
    __shared__ unsigned short tile[ROWS * TN];  // 40 KB bf16
    __shared__ float wlds[C];
    __shared__ float zl[L][TN];
    __shared__ float wsl[L][TN];

    const int t = threadIdx.x;

    // XCD-chunked swizzle: adjacent n-tiles -> same XCD L2 so the two 64 B
    // halves of each 128 B line merge. 3072 = 8 * 384.
    const int blk = (blockIdx.x & 7) * (NBLK / 8) + (blockIdx.x >> 3);
    const int n0 = blk * TN;

    wlds[t] = w[t];  // blockDim == 256 == C
    if (t < L * TN) ((float*)zl)[t] = 0.f;
    __syncthreads();

    const float bv = bptr[0];
    const int q = t & 3;    // float4 slot within the 16-float row (64 B/row)
    const int r0 = t >> 2;  // base row 0..63

    // ---- Phase 1: load + stage bf16 + z partials ----
    float za = 0.f, zb = 0.f, zc = 0.f, zd = 0.f;
#pragma unroll
    for (int k = 0; k < 20; ++k) {
        const int r = r0 + 64 * k;   // covers all 1280 rows
        const int c = r & 255;
        const float4 v = *(const float4*)(feats + (size_t)r * N + n0 + q * 4);
        ushort4 h;
        h.x = bf16rne(v.x); h.y = bf16rne(v.y);
        h.z = bf16rne(v.z); h.w = bf16rne(v.w);
        *(ushort4*)(&tile[r * TN + q * 4]) = h;  // byte addr = t*8 (+k*2048): conflict-free
        const float wc = wlds[c];
        za += wc * v.x; zb += wc * v.y; zc += wc * v.z; zd += wc * v.w;
        if ((k & 3) == 3) {
            // finished agent l = k>>2; reduce over the 16 lanes sharing q per wave
            const int l = k >> 2;
            float s0 = za, s1 = zb, s2 = zc, s3 = zd;
#pragma unroll
            for (int st = 4; st <= 32; st <<= 1) {
                s0 += __shfl_xor(s0, st);
                s1 += __shfl_xor(s1, st);
                s2 += __shfl_xor(s2, st);
                s3 += __shfl_xor(s3, st);
            }
            if ((t & 63) < 4) {  // lanes 0..3 of each wave, q = lane
                const int nn = (t & 3) * 4;
                atomicAdd(&zl[l][nn + 0], s0);
                atomicAdd(&zl[l][nn + 1], s1);
                atomicAdd(&zl[l][nn + 2], s2);
                atomicAdd(&zl[l][nn + 3], s3);
            }
            za = zb = zc = zd = 0.f;
        }
    }
    __syncthreads();

    // ---- Phase 2: Shapley + softmax (16 threads, one per pixel) ----
    if (t < TN) {
        float zv[L];
#pragma unroll
        for (int l = 0; l < L; ++l) zv[l] = zl[l][t];

        const float wcard[5] = {0.f, 0.05f, 1.f / 30.f, 0.05f, 0.2f};
        float shap[L];
#pragma unroll
        for (int i = 0; i < L; ++i) {
            int others[4];
            int kk = 0;
#pragma unroll
            for (int j = 0; j < L; ++j)
                if (j != i) others[kk++] = j;
            float acc = 0.f;
#pragma unroll
            for (int m = 1; m < 16; ++m) {
                float s = zv[i] + bv;
                int card = 0;
#pragma unroll
                for (int p = 0; p < 4; ++p)
                    if ((m >> p) & 1) { s += zv[others[p]]; ++card; }
                acc += wcard[card] * fmaxf(s, 0.f);
            }
            const float self = fmaxf(zv[i] + bv, 0.f);
            shap[i] = acc - 0.6f * self;  // -sum(wgt)=-0.8, +1/L=+0.2
        }
        float mx = shap[0];
#pragma unroll
        for (int i = 1; i < L; ++i) mx = fmaxf(mx, shap[i]);
        float e[L], sum = 0.f;
#pragma unroll
        for (int i = 0; i < L; ++i) { e[i] = __expf(shap[i] - mx); sum += e[i]; }
        const float inv = 1.f / sum;
#pragma unroll
        for (int i = 0; i < L; ++i) wsl[i][t] = e[i] * inv;
    }
    __syncthreads();

    // ---- Phase 3: weighted combine from bf16 tile, 64 B/row stores ----
    float wr[L][4];
#pragma unroll
    for (int l = 0; l < L; ++l)
#pragma unroll
        for (int j = 0; j < 4; ++j) wr[l][j] = wsl[l][q * 4 + j];

#pragma unroll
    for (int k2 = 0; k2 < 4; ++k2) {
        const int c = r0 + 64 * k2;
        float4 acc = make_float4(0.f, 0.f, 0.f, 0.f);
#pragma unroll
        for (int l = 0; l < L; ++l) {
            const ushort4 h = *(const ushort4*)(&tile[(l * 256 + c) * TN + q * 4]);
            acc.x += bf16tof(h.x) * wr[l][0];
            acc.y += bf16tof(h.y) * wr[l][1];
            acc.z += bf16tof(h.z) * wr[l][2];
            acc.w += bf16tof(h.w) * wr[l][3];
        }
        *(float4*)(out + (size_t)c * N + n0 + q * 4) = acc;
    }
}

extern "C" void kernel_launch(void* const* d_in, const int* in_sizes, int n_in,
                              void* d_out, int out_size, void* d_ws, size_t ws_size,
                              hipStream_t stream) {
    const float* feats = (const float*)d_in[0];
    const float* w     = (const float*)d_in[1];
    const float* bptr  = (const float*)d_in[2];
    float* out = (float*)d_out;

    k_fused<<<NBLK, 256, 0, stream>>>(feats, w, bptr, out);
}